// Round 15
// baseline (102.996 us; speedup 1.0000x reference)
//
#include <hip/hip_runtime.h>

#define D_MODEL 1024
#define N_MOD   4

typedef float fx4 __attribute__((ext_vector_type(4)));

// ============ Stage (R13-proven, comm-free): Weff = Wr . Wg ============
__global__ __launch_bounds__(256) void weff_skinny_kernel(
    const fx4*   __restrict__ Wg4,   // [1024][256] fx4
    const float* __restrict__ Wr,    // [4][1024]
    fx4*         __restrict__ Weff4) // [4][256] fx4
{
    const int t   = threadIdx.x;
    const int es  = t >> 1;               // 0..127
    const int c   = t & 1;                // 0..1
    const int col = blockIdx.x * 2 + c;   // fx4-column 0..255

    fx4 acc[N_MOD];
    #pragma unroll
    for (int m = 0; m < N_MOD; ++m) acc[m] = (fx4)(0.f);

    #pragma unroll
    for (int k = 0; k < 8; ++k) {
        const int e = es + k * 128;
        const fx4 wg = Wg4[e * 256 + col];
        #pragma unroll
        for (int m = 0; m < N_MOD; ++m)
            acc[m] += Wr[m * D_MODEL + e] * wg;
    }

    __shared__ fx4 red[2][N_MOD][128];          // 16KB
    #pragma unroll
    for (int m = 0; m < N_MOD; ++m) red[c][m][es] = acc[m];
    __syncthreads();

    const int p  = t >> 5;
    const int c2 = p & 1;
    const int m2 = p >> 1;
    const int e5 = t & 31;
    fx4 s = red[c2][m2][e5]      + red[c2][m2][e5 + 32]
          + red[c2][m2][e5 + 64] + red[c2][m2][e5 + 96];

    #pragma unroll
    for (int off = 16; off; off >>= 1) {
        s.x += __shfl_xor(s.x, off, 64);
        s.y += __shfl_xor(s.y, off, 64);
        s.z += __shfl_xor(s.z, off, 64);
        s.w += __shfl_xor(s.w, off, 64);
    }
    if (e5 == 0)
        Weff4[m2 * 256 + blockIdx.x * 2 + c2] = s;
}

// 4-row tree exchange: acc[4][4] (row, module) partials per lane -> full logit
// at every lane for (row=(lane>>2)&3, m=lane&3), replicated over lane bits 4,5.
// 17 shuffles total (vs 28 for 4x per-row fold+butterfly).
static __device__ __forceinline__ float tree_reduce4(const float acc[4][N_MOD],
                                                     int lane) {
    const bool b0 = lane & 1, b1 = lane & 2, b2 = lane & 4, b3 = lane & 8;
    float p01[4], p23[4], q[4];
    #pragma unroll
    for (int i = 0; i < 4; ++i) {
        p01[i] = (b0 ? acc[i][1] : acc[i][0])
               + __shfl_xor(b0 ? acc[i][0] : acc[i][1], 1, 64);
        p23[i] = (b0 ? acc[i][3] : acc[i][2])
               + __shfl_xor(b0 ? acc[i][2] : acc[i][3], 1, 64);
    }
    #pragma unroll
    for (int i = 0; i < 4; ++i)
        q[i] = (b1 ? p23[i] : p01[i])
             + __shfl_xor(b1 ? p01[i] : p23[i], 2, 64);
    const float r01 = (b2 ? q[1] : q[0]) + __shfl_xor(b2 ? q[0] : q[1], 4, 64);
    const float r23 = (b2 ? q[3] : q[2]) + __shfl_xor(b2 ? q[2] : q[3], 4, 64);
    float s = (b3 ? r23 : r01) + __shfl_xor(b3 ? r01 : r23, 8, 64);
    s += __shfl_xor(s, 16, 64);
    s += __shfl_xor(s, 32, 64);
    return s;
}

// hi decision for the 4 rows held in s (one (row,m) per lane, 4-lane module
// groups): prob_m > 0.5  <=>  m == argmax && S < 2 (ties -> S>=2 -> false).
static __device__ __forceinline__ bool hi_decide(float s) {
    float mx = fmaxf(s, __shfl_xor(s, 1, 64));
    mx = fmaxf(mx, __shfl_xor(mx, 2, 64));
    const float ex = expf(s - mx);            // argmax lane: exactly 1.0
    float S = ex + __shfl_xor(ex, 1, 64);
    S += __shfl_xor(S, 2, 64);
    return (s == mx) && (S < 2.0f);
}

// ============ Main v7: R13 loads/FMA + tree-reduce epilogue ============
__global__ __launch_bounds__(256, 4) void router_main_kernel(
    const float* __restrict__ h,     // [B, 1024]
    const float* __restrict__ Weff,  // [4, 1024]
    float* __restrict__ out,         // [4][B][4]
    int B)
{
    const int lane = threadIdx.x & 63;
    const int wave = threadIdx.x >> 6;

    fx4 w4[N_MOD][4];
    const fx4* __restrict__ W4 = (const fx4*)Weff;
    #pragma unroll
    for (int m = 0; m < N_MOD; ++m)
        #pragma unroll
        for (int c = 0; c < 4; ++c)
            w4[m][c] = W4[m * 256 + c * 64 + lane];

    float4* __restrict__ out4 = (float4*)out;   // [4][B] float4s
    const int wid  = blockIdx.x * 4 + wave;
    const int step = gridDim.x * 4 * 8;

    for (int row0 = wid * 8; row0 < B; row0 += step) {
        unsigned long long mA, mB;
        #pragma unroll
        for (int half = 0; half < 2; ++half) {
            float acc[4][N_MOD];
            #pragma unroll
            for (int i = 0; i < 4; ++i) {
                const int row = row0 + half * 4 + i;
                const fx4* __restrict__ h4 =
                    (const fx4*)(h + (size_t)row * D_MODEL);
                fx4 v[4];
                #pragma unroll
                for (int c = 0; c < 4; ++c) v[c] = h4[c * 64 + lane];
                #pragma unroll
                for (int m = 0; m < N_MOD; ++m) acc[i][m] = 0.f;
                #pragma unroll
                for (int c = 0; c < 4; ++c) {
                    #pragma unroll
                    for (int m = 0; m < N_MOD; ++m) {
                        acc[i][m] = fmaf(v[c].x, w4[m][c].x, acc[i][m]);
                        acc[i][m] = fmaf(v[c].y, w4[m][c].y, acc[i][m]);
                        acc[i][m] = fmaf(v[c].z, w4[m][c].z, acc[i][m]);
                        acc[i][m] = fmaf(v[c].w, w4[m][c].w, acc[i][m]);
                    }
                }
            }
            const float s = tree_reduce4(acc, lane);
            const bool hi = hi_decide(s);
            if (half == 0) mA = __ballot(hi);
            else           mB = __ballot(hi);
        }
        // lanes 0-31 write 4 full 128B lines: module m = l>>3, row offset l&7.
        // Source bit for (m, rs): batch rs>>2, lane ((rs&3)<<2)|m.
        const int m  = lane >> 3;
        const int rs = lane & 7;
        const int sl = ((rs & 3) << 2) | m;
        if (lane < 32) {
            const unsigned long long mm = (rs < 4) ? mA : mB;
            const bool hi = (mm >> sl) & 1;
            const float4 val = hi ? make_float4(0.5f, 0.5f, 0.f, 0.f)
                                  : make_float4(1.f, 0.f, 0.f, 0.f);
            out4[(size_t)m * B + row0 + rs] = val;
        }
    }
}

extern "C" void kernel_launch(void* const* d_in, const int* in_sizes, int n_in,
                              void* d_out, int out_size, void* d_ws, size_t ws_size,
                              hipStream_t stream) {
    const float* h  = (const float*)d_in[0];   // [B, 1024]
    const fx4*   Wg = (const fx4*)d_in[1];     // [1024, 1024] floats
    const float* Wr = (const float*)d_in[2];   // [4, 1024]
    float* out = (float*)d_out;                // [4][B][4]

    const int B = in_sizes[0] / D_MODEL;       // 32768

    float* Weff = (float*)d_ws;                // 16 KB

    weff_skinny_kernel<<<128, 256, 0, stream>>>(Wg, Wr, (fx4*)Weff);

    const int grid = (B + 8 * 4 - 1) / (8 * 4); // 1024 for B=32768
    router_main_kernel<<<grid, 256, 0, stream>>>(h, Weff, out, B);
}

// Round 16
// 33.886 us; speedup vs baseline: 3.0395x; 3.0395x over previous
//
#include <hip/hip_runtime.h>

#define D_MODEL 1024
#define N_MOD   4

typedef float fx4 __attribute__((ext_vector_type(4)));

// ============ Stage (R13-proven, comm-free): Weff = Wr . Wg ============
__global__ __launch_bounds__(256) void weff_skinny_kernel(
    const fx4*   __restrict__ Wg4,   // [1024][256] fx4
    const float* __restrict__ Wr,    // [4][1024]
    fx4*         __restrict__ Weff4) // [4][256] fx4
{
    const int t   = threadIdx.x;
    const int es  = t >> 1;               // 0..127
    const int c   = t & 1;                // 0..1
    const int col = blockIdx.x * 2 + c;   // fx4-column 0..255

    fx4 acc[N_MOD];
    #pragma unroll
    for (int m = 0; m < N_MOD; ++m) acc[m] = (fx4)(0.f);

    #pragma unroll
    for (int k = 0; k < 8; ++k) {
        const int e = es + k * 128;
        const fx4 wg = Wg4[e * 256 + col];
        #pragma unroll
        for (int m = 0; m < N_MOD; ++m)
            acc[m] += Wr[m * D_MODEL + e] * wg;
    }

    __shared__ fx4 red[2][N_MOD][128];          // 16KB
    #pragma unroll
    for (int m = 0; m < N_MOD; ++m) red[c][m][es] = acc[m];
    __syncthreads();

    const int p  = t >> 5;
    const int c2 = p & 1;
    const int m2 = p >> 1;
    const int e5 = t & 31;
    fx4 s = red[c2][m2][e5]      + red[c2][m2][e5 + 32]
          + red[c2][m2][e5 + 64] + red[c2][m2][e5 + 96];

    #pragma unroll
    for (int off = 16; off; off >>= 1) {
        s.x += __shfl_xor(s.x, off, 64);
        s.y += __shfl_xor(s.y, off, 64);
        s.z += __shfl_xor(s.z, off, 64);
        s.w += __shfl_xor(s.w, off, 64);
    }
    if (e5 == 0)
        Weff4[m2 * 256 + blockIdx.x * 2 + c2] = s;
}

// ============ Main v8: R13 loads/FMA + INLINE tree-reduce epilogue ============
__global__ __launch_bounds__(256) void router_main_kernel(
    const float* __restrict__ h,     // [B, 1024]
    const float* __restrict__ Weff,  // [4, 1024]
    float* __restrict__ out,         // [4][B][4]
    int B)
{
    const int lane = threadIdx.x & 63;
    const int wave = threadIdx.x >> 6;

    fx4 w4[N_MOD][4];
    const fx4* __restrict__ W4 = (const fx4*)Weff;
    #pragma unroll
    for (int m = 0; m < N_MOD; ++m)
        #pragma unroll
        for (int c = 0; c < 4; ++c)
            w4[m][c] = W4[m * 256 + c * 64 + lane];

    float4* __restrict__ out4 = (float4*)out;   // [4][B] float4s
    const int wid  = blockIdx.x * 4 + wave;
    const int step = gridDim.x * 4 * 8;

    const bool b0 = lane & 1, b1 = lane & 2, b2 = lane & 4, b3 = lane & 8;

    for (int row0 = wid * 8; row0 < B; row0 += step) {
        unsigned long long mhalf[2];
        #pragma unroll
        for (int half = 0; half < 2; ++half) {
            float acc[4][N_MOD];
            #pragma unroll
            for (int i = 0; i < 4; ++i) {
                const int row = row0 + half * 4 + i;
                const fx4* __restrict__ h4 =
                    (const fx4*)(h + (size_t)row * D_MODEL);
                fx4 v[4];
                #pragma unroll
                for (int c = 0; c < 4; ++c) v[c] = h4[c * 64 + lane];
                #pragma unroll
                for (int m = 0; m < N_MOD; ++m) acc[i][m] = 0.f;
                #pragma unroll
                for (int c = 0; c < 4; ++c) {
                    #pragma unroll
                    for (int m = 0; m < N_MOD; ++m) {
                        acc[i][m] = fmaf(v[c].x, w4[m][c].x, acc[i][m]);
                        acc[i][m] = fmaf(v[c].y, w4[m][c].y, acc[i][m]);
                        acc[i][m] = fmaf(v[c].z, w4[m][c].z, acc[i][m]);
                        acc[i][m] = fmaf(v[c].w, w4[m][c].w, acc[i][m]);
                    }
                }
            }
            // ---- inline tree exchange (all-static indices, no function call) ----
            // level 1 (xor 1, module bit0): 8 shuffles
            float p01[4], p23[4];
            #pragma unroll
            for (int i = 0; i < 4; ++i) {
                p01[i] = (b0 ? acc[i][1] : acc[i][0])
                       + __shfl_xor(b0 ? acc[i][0] : acc[i][1], 1, 64);
                p23[i] = (b0 ? acc[i][3] : acc[i][2])
                       + __shfl_xor(b0 ? acc[i][2] : acc[i][3], 1, 64);
            }
            // level 2 (xor 2, module bit1): 4 shuffles
            float q[4];
            #pragma unroll
            for (int i = 0; i < 4; ++i)
                q[i] = (b1 ? p23[i] : p01[i])
                     + __shfl_xor(b1 ? p01[i] : p23[i], 2, 64);
            // level 3 (xor 4, row bit0): 2 shuffles
            const float r01 = (b2 ? q[1] : q[0])
                            + __shfl_xor(b2 ? q[0] : q[1], 4, 64);
            const float r23 = (b2 ? q[3] : q[2])
                            + __shfl_xor(b2 ? q[2] : q[3], 4, 64);
            // level 4 (xor 8, row bit1): 1 shuffle
            float s = (b3 ? r23 : r01) + __shfl_xor(b3 ? r01 : r23, 8, 64);
            // levels 5,6 (xor 16, 32): finish the 1024-element dot
            s += __shfl_xor(s, 16, 64);
            s += __shfl_xor(s, 32, 64);
            // s = logit(row = (lane>>2)&3, m = lane&3), replicated on bits 4,5

            // softmax>0.5 within each 4-lane module group: 4 shuffles
            float mx = fmaxf(s, __shfl_xor(s, 1, 64));
            mx = fmaxf(mx, __shfl_xor(mx, 2, 64));
            const float ex = expf(s - mx);        // argmax lane: exactly 1.0
            float S = ex + __shfl_xor(ex, 1, 64);
            S += __shfl_xor(S, 2, 64);
            // prob_m > 0.5  <=>  m == argmax && S < 2 (ties -> S>=2 -> false)
            const bool hi = (s == mx) && (S < 2.0f);
            mhalf[half] = __ballot(hi);
        }
        // lanes 0-31 write 4 full 128B lines: module m = l>>3, row offset l&7.
        // Bit for (m, rs) lives in mhalf[rs>>2] at position ((rs&3)<<2)|m.
        const int m  = lane >> 3;
        const int rs = lane & 7;
        const int sl = ((rs & 3) << 2) | m;
        if (lane < 32) {
            const unsigned long long mm = (rs < 4) ? mhalf[0] : mhalf[1];
            const bool hi = (mm >> sl) & 1;
            const float4 val = hi ? make_float4(0.5f, 0.5f, 0.f, 0.f)
                                  : make_float4(1.f, 0.f, 0.f, 0.f);
            out4[(size_t)m * B + row0 + rs] = val;
        }
    }
}

extern "C" void kernel_launch(void* const* d_in, const int* in_sizes, int n_in,
                              void* d_out, int out_size, void* d_ws, size_t ws_size,
                              hipStream_t stream) {
    const float* h  = (const float*)d_in[0];   // [B, 1024]
    const fx4*   Wg = (const fx4*)d_in[1];     // [1024, 1024] floats
    const float* Wr = (const float*)d_in[2];   // [4, 1024]
    float* out = (float*)d_out;                // [4][B][4]

    const int B = in_sizes[0] / D_MODEL;       // 32768

    float* Weff = (float*)d_ws;                // 16 KB

    weff_skinny_kernel<<<128, 256, 0, stream>>>(Wg, Wr, (fx4*)Weff);

    const int grid = (B + 8 * 4 - 1) / (8 * 4); // 1024 for B=32768
    router_main_kernel<<<grid, 256, 0, stream>>>(h, Weff, out, B);
}

// Round 17
// 32.143 us; speedup vs baseline: 3.2043x; 1.0542x over previous
//
#include <hip/hip_runtime.h>

#define D_MODEL 1024
#define N_MOD   4

typedef float fx4 __attribute__((ext_vector_type(4)));

// ============ Stage (R13-proven, comm-free): Weff = Wr . Wg ============
// 128 blocks; block b owns fx4-columns {2b, 2b+1}; Wg read exactly once
// grid-wide; in-block 128-way e-reduction via LDS fold + half-wave shuffle.
__global__ __launch_bounds__(256) void weff_skinny_kernel(
    const fx4*   __restrict__ Wg4,   // [1024][256] fx4
    const float* __restrict__ Wr,    // [4][1024]
    fx4*         __restrict__ Weff4) // [4][256] fx4
{
    const int t   = threadIdx.x;
    const int es  = t >> 1;               // 0..127
    const int c   = t & 1;                // 0..1
    const int col = blockIdx.x * 2 + c;   // fx4-column 0..255

    fx4 acc[N_MOD];
    #pragma unroll
    for (int m = 0; m < N_MOD; ++m) acc[m] = (fx4)(0.f);

    #pragma unroll
    for (int k = 0; k < 8; ++k) {
        const int e = es + k * 128;
        const fx4 wg = Wg4[e * 256 + col];
        #pragma unroll
        for (int m = 0; m < N_MOD; ++m)
            acc[m] += Wr[m * D_MODEL + e] * wg;
    }

    __shared__ fx4 red[2][N_MOD][128];          // 16KB
    #pragma unroll
    for (int m = 0; m < N_MOD; ++m) red[c][m][es] = acc[m];
    __syncthreads();

    const int p  = t >> 5;
    const int c2 = p & 1;
    const int m2 = p >> 1;
    const int e5 = t & 31;
    fx4 s = red[c2][m2][e5]      + red[c2][m2][e5 + 32]
          + red[c2][m2][e5 + 64] + red[c2][m2][e5 + 96];

    #pragma unroll
    for (int off = 16; off; off >>= 1) {
        s.x += __shfl_xor(s.x, off, 64);
        s.y += __shfl_xor(s.y, off, 64);
        s.z += __shfl_xor(s.z, off, 64);
        s.w += __shfl_xor(s.w, off, 64);
    }
    if (e5 == 0)
        Weff4[m2 * 256 + blockIdx.x * 2 + c2] = s;
}

// ============ Main (R8/R13-proven): 8 rows/wave, folded reduce, line stores ====
__global__ __launch_bounds__(256) void router_main_kernel(
    const float* __restrict__ h,     // [B, 1024]
    const float* __restrict__ Weff,  // [4, 1024]
    float* __restrict__ out,         // [4][B][4]
    int B)
{
    const int lane = threadIdx.x & 63;
    const int wave = threadIdx.x >> 6;

    fx4 w4[N_MOD][4];
    const fx4* __restrict__ W4 = (const fx4*)Weff;
    #pragma unroll
    for (int m = 0; m < N_MOD; ++m)
        #pragma unroll
        for (int c = 0; c < 4; ++c)
            w4[m][c] = W4[m * 256 + c * 64 + lane];

    float4* __restrict__ out4 = (float4*)out;   // [4][B] float4s
    const int wid  = blockIdx.x * 4 + wave;
    const int step = gridDim.x * 4 * 8;

    for (int row0 = wid * 8; row0 < B; row0 += step) {
        unsigned mask = 0;
        #pragma unroll
        for (int i = 0; i < 8; ++i) {
            const int row = row0 + i;
            const fx4* __restrict__ h4 = (const fx4*)(h + (size_t)row * D_MODEL);
            fx4 v[4];
            #pragma unroll
            for (int c = 0; c < 4; ++c) v[c] = h4[c * 64 + lane];

            float acc[N_MOD] = {0.f, 0.f, 0.f, 0.f};
            #pragma unroll
            for (int c = 0; c < 4; ++c) {
                #pragma unroll
                for (int m = 0; m < N_MOD; ++m) {
                    acc[m] = fmaf(v[c].x, w4[m][c].x, acc[m]);
                    acc[m] = fmaf(v[c].y, w4[m][c].y, acc[m]);
                    acc[m] = fmaf(v[c].z, w4[m][c].z, acc[m]);
                    acc[m] = fmaf(v[c].w, w4[m][c].w, acc[m]);
                }
            }
            // Fold 4 streams into lane%4, then butterfly: 7 shuffles total.
            const bool b0 = lane & 1;
            float a  = (b0 ? acc[1] : acc[0]) + __shfl_xor(b0 ? acc[0] : acc[1], 1, 64);
            float cc = (b0 ? acc[3] : acc[2]) + __shfl_xor(b0 ? acc[2] : acc[3], 1, 64);
            const bool b1 = lane & 2;
            float r  = (b1 ? cc : a) + __shfl_xor(b1 ? a : cc, 2, 64);
            r += __shfl_xor(r, 4, 64);
            r += __shfl_xor(r, 8, 64);
            r += __shfl_xor(r, 16, 64);
            r += __shfl_xor(r, 32, 64);
            // r = logit of module lane&3 (replicated across each 4-lane group)
            float mx = fmaxf(r, __shfl_xor(r, 1, 64));
            mx = fmaxf(mx, __shfl_xor(mx, 2, 64));
            const float ex = expf(r - mx);       // argmax lane: exactly 1.0
            float S = ex + __shfl_xor(ex, 1, 64);
            S = S + __shfl_xor(S, 2, 64);
            // prob_m > 0.5  <=>  m == argmax  &&  S < 2
            const bool hi = (r == mx) && (S < 2.0f);
            mask |= (hi ? 1u : 0u) << i;
        }
        // lanes 0-31 write 4 full 128B lines: module m = l>>3, row offset l&7
        const int m = lane >> 3;
        const int rs = lane & 7;
        const unsigned mm = __shfl(mask, m, 64); // lane m holds module m's mask
        if (lane < 32) {
            const bool hi = (mm >> rs) & 1;
            const float4 val = hi ? make_float4(0.5f, 0.5f, 0.f, 0.f)
                                  : make_float4(1.f, 0.f, 0.f, 0.f);
            out4[(size_t)m * B + row0 + rs] = val;
        }
    }
}

extern "C" void kernel_launch(void* const* d_in, const int* in_sizes, int n_in,
                              void* d_out, int out_size, void* d_ws, size_t ws_size,
                              hipStream_t stream) {
    const float* h  = (const float*)d_in[0];   // [B, 1024]
    const fx4*   Wg = (const fx4*)d_in[1];     // [1024, 1024] floats
    const float* Wr = (const float*)d_in[2];   // [4, 1024]
    float* out = (float*)d_out;                // [4][B][4]

    const int B = in_sizes[0] / D_MODEL;       // 32768

    float* Weff = (float*)d_ws;                // 16 KB

    weff_skinny_kernel<<<128, 256, 0, stream>>>(Wg, Wr, (fx4*)Weff);

    const int grid = (B + 8 * 4 - 1) / (8 * 4); // 1024 for B=32768
    router_main_kernel<<<grid, 256, 0, stream>>>(h, Weff, out, B);
}